// Round 12
// baseline (773.347 us; speedup 1.0000x reference)
//
#include <hip/hip_runtime.h>

#define N_NODES 100000
#define N_EDGES 1600000
#define N_GRAPHS 64

typedef __attribute__((ext_vector_type(8))) short bf16x8;
typedef __attribute__((ext_vector_type(4))) float f32x4;

// fp32 -> bf16 with round-to-nearest-even
__device__ __forceinline__ unsigned int f2bf(float f) {
  unsigned int u = __float_as_uint(f);
  return (u + 0x7FFFu + ((u >> 16) & 1u)) >> 16;
}
#define BLO(u) __uint_as_float((u) << 16)
#define BHI(u) __uint_as_float((u) & 0xFFFF0000u)

// split 8 consecutive fp32 into hi/lo bf16x8 fragments (relative err ~2^-16)
__device__ __forceinline__ void split8(const float* __restrict__ p, bf16x8& hi, bf16x8& lo) {
  float4 v0 = *(const float4*)p;
  float4 v1 = *(const float4*)(p + 4);
  unsigned h0 = f2bf(v0.x), h1 = f2bf(v0.y), h2 = f2bf(v0.z), h3 = f2bf(v0.w);
  unsigned h4 = f2bf(v1.x), h5 = f2bf(v1.y), h6 = f2bf(v1.z), h7 = f2bf(v1.w);
  hi[0] = (short)h0; hi[1] = (short)h1; hi[2] = (short)h2; hi[3] = (short)h3;
  hi[4] = (short)h4; hi[5] = (short)h5; hi[6] = (short)h6; hi[7] = (short)h7;
  lo[0] = (short)f2bf(v0.x - __uint_as_float(h0 << 16));
  lo[1] = (short)f2bf(v0.y - __uint_as_float(h1 << 16));
  lo[2] = (short)f2bf(v0.z - __uint_as_float(h2 << 16));
  lo[3] = (short)f2bf(v0.w - __uint_as_float(h3 << 16));
  lo[4] = (short)f2bf(v1.x - __uint_as_float(h4 << 16));
  lo[5] = (short)f2bf(v1.y - __uint_as_float(h5 << 16));
  lo[6] = (short)f2bf(v1.z - __uint_as_float(h6 << 16));
  lo[7] = (short)f2bf(v1.w - __uint_as_float(h7 << 16));
}

// ---------------- CSR build ----------------

__global__ __launch_bounds__(256) void k_zero_int(int* __restrict__ p, int n) {
  int i = blockIdx.x * 256 + threadIdx.x;
  if (i < n) p[i] = 0;
}

__global__ __launch_bounds__(256) void k_hist(const int* __restrict__ ei, int* __restrict__ deg) {
  int e = blockIdx.x * 256 + threadIdx.x;
  if (e < N_EDGES) atomicAdd(&deg[__builtin_nontemporal_load(&ei[N_EDGES + e])], 1);
}

__global__ __launch_bounds__(256) void k_scan1(const int* __restrict__ deg, int* __restrict__ part,
                                               int* __restrict__ bsum) {
  __shared__ int tmp[256];
  int i = blockIdx.x * 256 + threadIdx.x;
  int v = (i < N_NODES) ? deg[i] : 0;
  tmp[threadIdx.x] = v;
  __syncthreads();
  for (int o = 1; o < 256; o <<= 1) {
    int t = (threadIdx.x >= o) ? tmp[threadIdx.x - o] : 0;
    __syncthreads();
    tmp[threadIdx.x] += t;
    __syncthreads();
  }
  if (i < N_NODES) part[i] = tmp[threadIdx.x] - v;  // exclusive
  if (threadIdx.x == 255) bsum[blockIdx.x] = tmp[255];
}

__global__ __launch_bounds__(512) void k_scan2(const int* __restrict__ bsum, int* __restrict__ boff, int nb) {
  __shared__ int tmp[512];
  int v = ((int)threadIdx.x < nb) ? bsum[threadIdx.x] : 0;
  tmp[threadIdx.x] = v;
  __syncthreads();
  for (int o = 1; o < 512; o <<= 1) {
    int t = (threadIdx.x >= o) ? tmp[threadIdx.x - o] : 0;
    __syncthreads();
    tmp[threadIdx.x] += t;
    __syncthreads();
  }
  if ((int)threadIdx.x < nb) boff[threadIdx.x] = tmp[threadIdx.x] - v;  // exclusive
}

__global__ __launch_bounds__(256) void k_scan3(const int* __restrict__ part, const int* __restrict__ boff,
                                               int* __restrict__ rowptr, int* __restrict__ cursor) {
  int i = blockIdx.x * 256 + threadIdx.x;
  if (i < N_NODES) {
    int r = part[i] + boff[i >> 8];
    rowptr[i] = r;
    cursor[i] = r;
  } else if (i == N_NODES) {
    rowptr[N_NODES] = N_EDGES;
  }
}

// XCD-partitioned windowed fill (round 6) + NT edge reads (round 12):
// ei is stream-once; NT loads keep it from evicting the L2-resident csr
// window lines before they accumulate all ~16 scattered 4B writes.
#define FW_NPW 12500
#define FW_EPS 12500
__global__ __launch_bounds__(256) void k_fill_win(const int* __restrict__ ei, int* __restrict__ cursor,
                                                  int* __restrict__ csr) {
  int bid = blockIdx.x;
  int w = bid & 7;
  int s = bid >> 3;
  int lo = w * FW_NPW, hi = lo + FW_NPW;
  int e0 = s * FW_EPS, e1 = e0 + FW_EPS;
  for (int e = e0 + threadIdx.x; e < e1; e += 256) {
    int d = __builtin_nontemporal_load(&ei[N_EDGES + e]);
    if (d >= lo && d < hi) {
      int p = atomicAdd(&cursor[d], 1);
      csr[p] = __builtin_nontemporal_load(&ei[e]);
    }
  }
}

// ---------------- weight prep: transposed hi/lo bf16 split ----------------
__global__ __launch_bounds__(256) void k_prep_w(const float* __restrict__ w, unsigned short* __restrict__ wt) {
  int t = blockIdx.x * 256 + threadIdx.x;  // 16384 threads
  int k = t >> 7, c = t & 127;
  float v = w[k * 128 + c];
  unsigned int hi = f2bf(v);
  float vhi = __uint_as_float(hi << 16);
  unsigned int lo = f2bf(v - vhi);
  wt[c * 256 + k] = (unsigned short)hi;
  wt[c * 256 + k + 128] = (unsigned short)lo;
}

// ---------------- Layer 1 (IN_CH=4) ----------------

__global__ __launch_bounds__(256) void k_l1_agg(const float* __restrict__ x, const int* __restrict__ rowptr,
                                                const int* __restrict__ csr, float* __restrict__ agg4) {
  int t = blockIdx.x * 256 + threadIdx.x;
  if (t >= N_NODES * 4) return;
  int node = t >> 2, c = t & 3;
  int s = rowptr[node], e = rowptr[node + 1];
  float a = 0.f;
  for (int p = s; p < e; ++p) a += x[(size_t)csr[p] * 4 + c];
  agg4[t] = a;
}

// emits fp32 h (state) AND bf16 shadow (gather source) — round-7 numerics
__global__ __launch_bounds__(256) void k_l1_comb(const float* __restrict__ x, const float* __restrict__ agg4,
                                                 const float* __restrict__ w_rel, const float* __restrict__ b_rel,
                                                 const float* __restrict__ w_root, float* __restrict__ out,
                                                 unsigned short* __restrict__ hb) {
  int t = blockIdx.x * 256 + threadIdx.x;
  int node = t >> 7, c = t & 127;
  if (node >= N_NODES) return;
  float acc = b_rel[c];
#pragma unroll
  for (int k = 0; k < 4; ++k) acc += agg4[node * 4 + k] * w_rel[k * 128 + c];
#pragma unroll
  for (int k = 0; k < 4; ++k) acc += x[node * 4 + k] * w_root[k * 128 + c];
  float r = fmaxf(acc, 0.f);
  out[(size_t)node * 128 + c] = r;
  hb[(size_t)node * 128 + c] = (unsigned short)f2bf(r);
}

// ---------------- Layers 2-4: bf16 gather-sum -> fp32 agg ----------------
// 16 lanes per dst row, uint4/lane (8 bf16 = 16B) => 256B/row coalesced.
// unroll 8: 8 uint4 in flight per lane. csr reads NT (stream-once).
#define AGG_ACC(U)                                                    \
  a0.x += BLO((U).x); a0.y += BHI((U).x);                             \
  a0.z += BLO((U).y); a0.w += BHI((U).y);                             \
  a1.x += BLO((U).z); a1.y += BHI((U).z);                             \
  a1.z += BLO((U).w); a1.w += BHI((U).w);

__global__ __launch_bounds__(256) void k_agg_bf(const unsigned short* __restrict__ hb,
                                                const int* __restrict__ rowptr, const int* __restrict__ csr,
                                                float* __restrict__ aggout) {
  int node = (blockIdx.x * 256 + threadIdx.x) >> 4;
  int l = threadIdx.x & 15;
  if (node >= N_NODES) return;
  int s = rowptr[node], e = rowptr[node + 1];
  float4 a0 = make_float4(0.f, 0.f, 0.f, 0.f);
  float4 a1 = make_float4(0.f, 0.f, 0.f, 0.f);
  int p = s;
  for (; p + 8 <= e; p += 8) {
    int s0 = __builtin_nontemporal_load(&csr[p]);
    int s1 = __builtin_nontemporal_load(&csr[p + 1]);
    int s2 = __builtin_nontemporal_load(&csr[p + 2]);
    int s3 = __builtin_nontemporal_load(&csr[p + 3]);
    int s4 = __builtin_nontemporal_load(&csr[p + 4]);
    int s5 = __builtin_nontemporal_load(&csr[p + 5]);
    int s6 = __builtin_nontemporal_load(&csr[p + 6]);
    int s7 = __builtin_nontemporal_load(&csr[p + 7]);
    uint4 u0 = *(const uint4*)&hb[(size_t)s0 * 128 + l * 8];
    uint4 u1 = *(const uint4*)&hb[(size_t)s1 * 128 + l * 8];
    uint4 u2 = *(const uint4*)&hb[(size_t)s2 * 128 + l * 8];
    uint4 u3 = *(const uint4*)&hb[(size_t)s3 * 128 + l * 8];
    uint4 u4 = *(const uint4*)&hb[(size_t)s4 * 128 + l * 8];
    uint4 u5 = *(const uint4*)&hb[(size_t)s5 * 128 + l * 8];
    uint4 u6 = *(const uint4*)&hb[(size_t)s6 * 128 + l * 8];
    uint4 u7 = *(const uint4*)&hb[(size_t)s7 * 128 + l * 8];
    AGG_ACC(u0) AGG_ACC(u1) AGG_ACC(u2) AGG_ACC(u3)
    AGG_ACC(u4) AGG_ACC(u5) AGG_ACC(u6) AGG_ACC(u7)
  }
  for (; p + 4 <= e; p += 4) {
    int s0 = csr[p], s1 = csr[p + 1], s2 = csr[p + 2], s3 = csr[p + 3];
    uint4 u0 = *(const uint4*)&hb[(size_t)s0 * 128 + l * 8];
    uint4 u1 = *(const uint4*)&hb[(size_t)s1 * 128 + l * 8];
    uint4 u2 = *(const uint4*)&hb[(size_t)s2 * 128 + l * 8];
    uint4 u3 = *(const uint4*)&hb[(size_t)s3 * 128 + l * 8];
    AGG_ACC(u0) AGG_ACC(u1) AGG_ACC(u2) AGG_ACC(u3)
  }
  for (; p < e; ++p) {
    int s0 = csr[p];
    uint4 u = *(const uint4*)&hb[(size_t)s0 * 128 + l * 8];
    AGG_ACC(u)
  }
  *(float4*)&aggout[(size_t)node * 128 + l * 8] = a0;
  *(float4*)&aggout[(size_t)node * 128 + l * 8 + 4] = a1;
}

// ---------------- Layers 2-4: MFMA dual GEMM, LDS-staged swizzled B --------
// (round 10 — unchanged) out = relu(agg @ w_rel + h @ w_root + bias).
__global__ __launch_bounds__(256) void k_gemm_mfma3(
    const float* __restrict__ agg, const float* __restrict__ h,
    const unsigned short* __restrict__ wrelT, const unsigned short* __restrict__ wrootT,
    const float* __restrict__ bias, const int last,
    float* __restrict__ hout, unsigned short* __restrict__ hbout) {
  __shared__ char lds[32768];
  const int tid = threadIdx.x;
  const int wave = tid >> 6;
  const int lane = tid & 63;
  const int l15 = lane & 15;
  const int lg = lane >> 4;
  const int rb = blockIdx.x * 64 + wave * 16;
  int ar = rb + l15;
  if (ar >= N_NODES) ar = N_NODES - 1;

  f32x4 acc[8];
#pragma unroll
  for (int i = 0; i < 8; ++i) acc[i] = (f32x4){0.f, 0.f, 0.f, 0.f};

#pragma unroll
  for (int src = 0; src < 2; ++src) {
    const float* A = src ? h : agg;
    const unsigned short* W = src ? wrootT : wrelT;
    const float* arow = A + (size_t)ar * 128 + lg * 8;
    bf16x8 ah0, al0, ah1, al1, ah2, al2, ah3, al3;
    split8(arow, ah0, al0);
    split8(arow + 32, ah1, al1);
    split8(arow + 64, ah2, al2);
    split8(arow + 96, ah3, al3);
#pragma unroll
    for (int half = 0; half < 2; ++half) {
      __syncthreads();  // previous chunk's readers done
      const unsigned short* wsrc = W + half * 16384;
#pragma unroll
      for (int i = 0; i < 8; ++i) {
        int f = i * 2048 + tid * 8;
        int col = f >> 8;
        int kb2 = (f & 255) * 2;
        uint4 v = *(const uint4*)(wsrc + f);
        *(uint4*)&lds[col * 512 + (kb2 ^ ((col & 7) << 4))] = v;
      }
      __syncthreads();
#pragma unroll
      for (int c0l = 0; c0l < 4; ++c0l) {
        const int c0 = half * 4 + c0l;
        const int cl = c0l * 16 + l15;
        const char* bp = lds + cl * 512;
        const int sw = (cl & 7) << 4;
        const int o = lg * 16;
        bf16x8 bh0 = *(const bf16x8*)(bp + ((o) ^ sw));
        bf16x8 bh1 = *(const bf16x8*)(bp + ((64 + o) ^ sw));
        bf16x8 bh2 = *(const bf16x8*)(bp + ((128 + o) ^ sw));
        bf16x8 bh3 = *(const bf16x8*)(bp + ((192 + o) ^ sw));
        bf16x8 bl0 = *(const bf16x8*)(bp + ((256 + o) ^ sw));
        bf16x8 bl1 = *(const bf16x8*)(bp + ((320 + o) ^ sw));
        bf16x8 bl2 = *(const bf16x8*)(bp + ((384 + o) ^ sw));
        bf16x8 bl3 = *(const bf16x8*)(bp + ((448 + o) ^ sw));
        acc[c0] = __builtin_amdgcn_mfma_f32_16x16x32_bf16(ah0, bh0, acc[c0], 0, 0, 0);
        acc[c0] = __builtin_amdgcn_mfma_f32_16x16x32_bf16(ah1, bh1, acc[c0], 0, 0, 0);
        acc[c0] = __builtin_amdgcn_mfma_f32_16x16x32_bf16(ah2, bh2, acc[c0], 0, 0, 0);
        acc[c0] = __builtin_amdgcn_mfma_f32_16x16x32_bf16(ah3, bh3, acc[c0], 0, 0, 0);
        acc[c0] = __builtin_amdgcn_mfma_f32_16x16x32_bf16(ah0, bl0, acc[c0], 0, 0, 0);
        acc[c0] = __builtin_amdgcn_mfma_f32_16x16x32_bf16(ah1, bl1, acc[c0], 0, 0, 0);
        acc[c0] = __builtin_amdgcn_mfma_f32_16x16x32_bf16(ah2, bl2, acc[c0], 0, 0, 0);
        acc[c0] = __builtin_amdgcn_mfma_f32_16x16x32_bf16(ah3, bl3, acc[c0], 0, 0, 0);
        acc[c0] = __builtin_amdgcn_mfma_f32_16x16x32_bf16(al0, bh0, acc[c0], 0, 0, 0);
        acc[c0] = __builtin_amdgcn_mfma_f32_16x16x32_bf16(al1, bh1, acc[c0], 0, 0, 0);
        acc[c0] = __builtin_amdgcn_mfma_f32_16x16x32_bf16(al2, bh2, acc[c0], 0, 0, 0);
        acc[c0] = __builtin_amdgcn_mfma_f32_16x16x32_bf16(al3, bh3, acc[c0], 0, 0, 0);
      }
    }
  }

#pragma unroll
  for (int c0 = 0; c0 < 8; ++c0) {
    const int c = c0 * 16 + l15;
    const float bi = bias[c];
#pragma unroll
    for (int j = 0; j < 4; ++j) {
      const int row = rb + lg * 4 + j;
      if (row < N_NODES) {
        float v = fmaxf(acc[c0][j] + bi, 0.f);
        hout[(size_t)row * 128 + c] = v;
        if (!last) hbout[(size_t)row * 128 + c] = (unsigned short)f2bf(v);
      }
    }
  }
}

// ---------------- Pooling ----------------

__device__ __forceinline__ int lower_bound_batch(const int* __restrict__ batch, int key) {
  int lo = 0, hi = N_NODES;
  while (lo < hi) {
    int mid = (lo + hi) >> 1;
    if (batch[mid] < key) lo = mid + 1;
    else hi = mid;
  }
  return lo;
}

__global__ __launch_bounds__(256) void k_pool1(const float* __restrict__ h, const int* __restrict__ batch,
                                               float* __restrict__ psum, float* __restrict__ pmax) {
  int b = blockIdx.x;
  int g = b >> 2, q = b & 3;
  int start = lower_bound_batch(batch, g);
  int end = lower_bound_batch(batch, g + 1);
  int c = threadIdx.x & 127;
  int half = threadIdx.x >> 7;
  float sum = 0.f, mx = -3.0e38f;
  for (int n = start + q * 2 + half; n < end; n += 8) {
    float v = h[(size_t)n * 128 + c];
    sum += v;
    mx = fmaxf(mx, v);
  }
  __shared__ float ss[128], sm[128];
  if (half == 0) { ss[c] = sum; sm[c] = mx; }
  __syncthreads();
  if (half == 1) { ss[c] += sum; sm[c] = fmaxf(sm[c], mx); }
  __syncthreads();
  if (half == 0) {
    psum[(size_t)b * 128 + c] = ss[c];
    pmax[(size_t)b * 128 + c] = sm[c];
  }
}

__global__ __launch_bounds__(128) void k_pool2(const float* __restrict__ psum, const float* __restrict__ pmax,
                                               const int* __restrict__ batch, float* __restrict__ pooled) {
  int g = blockIdx.x;
  int c = threadIdx.x;
  int start = lower_bound_batch(batch, g), end = lower_bound_batch(batch, g + 1);
  int count = end - start;
  float s = 0.f, m = -3.0e38f;
#pragma unroll
  for (int q = 0; q < 4; ++q) {
    s += psum[(size_t)(g * 4 + q) * 128 + c];
    m = fmaxf(m, pmax[(size_t)(g * 4 + q) * 128 + c]);
  }
  pooled[(size_t)g * 256 + c] = (count > 0) ? m : 0.f;
  pooled[(size_t)g * 256 + 128 + c] = s / fmaxf((float)count, 1.f);
}

// ---------------- Final FC (fused metadata branch) ----------------

__global__ __launch_bounds__(128) void k_fc(const float* __restrict__ pooled, const float* __restrict__ metadata,
                                            const float* __restrict__ convm_w, const float* __restrict__ convm_b,
                                            const float* __restrict__ fc_w, const float* __restrict__ fc_b,
                                            const float* __restrict__ fc2_w, const float* __restrict__ fc2_b,
                                            float* __restrict__ out) {
  int g = blockIdx.x;
  int tid = threadIdx.x;
  __shared__ float xc[260];
  xc[tid] = pooled[(size_t)g * 256 + tid];
  xc[128 + tid] = pooled[(size_t)g * 256 + 128 + tid];
  if (tid < 4) xc[256 + tid] = fmaxf(metadata[g] * convm_w[tid] + convm_b[tid], 0.f);
  __syncthreads();
  float acc = fc_b[tid];
  for (int k = 0; k < 260; ++k) acc += xc[k] * fc_w[(size_t)k * 128 + tid];
  float partial = fmaxf(acc, 0.f) * fc2_w[tid];
#pragma unroll
  for (int off = 32; off > 0; off >>= 1) partial += __shfl_down(partial, off);
  __shared__ float wred[2];
  if ((tid & 63) == 0) wred[tid >> 6] = partial;
  __syncthreads();
  if (tid == 0) out[g] = wred[0] + wred[1] + fc2_b[0];
}

// ---------------- launch ----------------

extern "C" void kernel_launch(void* const* d_in, const int* in_sizes, int n_in,
                              void* d_out, int out_size, void* d_ws, size_t ws_size,
                              hipStream_t stream) {
  const float* x = (const float*)d_in[0];
  const float* metadata = (const float*)d_in[1];
  const int* ei = (const int*)d_in[2];
  const int* batch = (const int*)d_in[3];
  const float* w_rel[4] = {(const float*)d_in[4], (const float*)d_in[7], (const float*)d_in[10], (const float*)d_in[13]};
  const float* b_rel[4] = {(const float*)d_in[5], (const float*)d_in[8], (const float*)d_in[11], (const float*)d_in[14]};
  const float* w_root[4] = {(const float*)d_in[6], (const float*)d_in[9], (const float*)d_in[12], (const float*)d_in[15]};
  const float* convm_w = (const float*)d_in[16];
  const float* convm_b = (const float*)d_in[17];
  const float* fc_w = (const float*)d_in[18];
  const float* fc_b = (const float*)d_in[19];
  const float* fc2_w = (const float*)d_in[20];
  const float* fc2_b = (const float*)d_in[21];
  float* out = (float*)d_out;

  char* ws = (char*)d_ws;
  size_t off = 0;
  auto alloc = [&](size_t bytes) {
    off = (off + 255) & ~(size_t)255;
    void* p = ws + off;
    off += bytes;
    return p;
  };
  int* deg = (int*)alloc((size_t)N_NODES * 4);
  int* rowptr = (int*)alloc((size_t)(N_NODES + 1) * 4);
  int* cursor = (int*)alloc((size_t)N_NODES * 4);
  int* bsum = (int*)alloc(512 * 4);
  int* boff = (int*)alloc(512 * 4);
  int* csr = (int*)alloc((size_t)N_EDGES * 4);
  float* agg4 = (float*)alloc((size_t)N_NODES * 4 * 4);
  float* bufA = (float*)alloc((size_t)N_NODES * 128 * 4);                   // h fp32 state
  float* bufB = (float*)alloc((size_t)N_NODES * 128 * 4);                   // agg fp32
  unsigned short* hb = (unsigned short*)alloc((size_t)N_NODES * 128 * 2);   // h bf16 (gather src)
  unsigned short* wt = (unsigned short*)alloc((size_t)6 * 128 * 256 * 2);   // transposed hi/lo weights
  float* psum = (float*)alloc((size_t)256 * 128 * 4);
  float* pmax = (float*)alloc((size_t)256 * 128 * 4);
  float* pooled = (float*)alloc((size_t)64 * 256 * 4);

  const int nblk_nodes = (N_NODES + 255) / 256;
  const int nblk_edges = (N_EDGES + 255) / 256;

  // weight prep (independent)
  for (int l = 1; l < 4; ++l) {
    k_prep_w<<<64, 256, 0, stream>>>(w_rel[l], wt + (size_t)(2 * (l - 1)) * 32768);
    k_prep_w<<<64, 256, 0, stream>>>(w_root[l], wt + (size_t)(2 * (l - 1) + 1) * 32768);
  }

  // CSR build
  k_zero_int<<<nblk_nodes, 256, 0, stream>>>(deg, N_NODES);
  k_hist<<<nblk_edges, 256, 0, stream>>>(ei, deg);
  k_scan1<<<nblk_nodes, 256, 0, stream>>>(deg, rowptr, bsum);
  k_scan2<<<1, 512, 0, stream>>>(bsum, boff, nblk_nodes);
  k_scan3<<<(N_NODES + 1 + 255) / 256, 256, 0, stream>>>(rowptr, boff, rowptr, cursor);
  k_fill_win<<<8 * 128, 256, 0, stream>>>(ei, cursor, csr);

  // Layer 1 (fp32 math, fp32 + bf16 outputs)
  k_l1_agg<<<(N_NODES * 4 + 255) / 256, 256, 0, stream>>>(x, rowptr, csr, agg4);
  k_l1_comb<<<(N_NODES * 128 + 255) / 256, 256, 0, stream>>>(x, agg4, w_rel[0], b_rel[0], w_root[0], bufA, hb);

  // Layers 2-4: bf16 gather (hb -> bufB fp32), MFMA GEMM (bufB,bufA -> bufA[,hb])
  for (int l = 1; l < 4; ++l) {
    k_agg_bf<<<(N_NODES * 16 + 255) / 256, 256, 0, stream>>>(hb, rowptr, csr, bufB);
    k_gemm_mfma3<<<(N_NODES + 63) / 64, 256, 0, stream>>>(
        bufB, bufA, wt + (size_t)(2 * (l - 1)) * 32768, wt + (size_t)(2 * (l - 1) + 1) * 32768,
        b_rel[l], (l == 3) ? 1 : 0, bufA, hb);
  }

  // Pool + FC
  k_pool1<<<256, 256, 0, stream>>>(bufA, batch, psum, pmax);
  k_pool2<<<64, 128, 0, stream>>>(psum, pmax, batch, pooled);
  k_fc<<<64, 128, 0, stream>>>(pooled, metadata, convm_w, convm_b, fc_w, fc_b, fc2_w, fc2_b, out);
}

// Round 15
// 710.907 us; speedup vs baseline: 1.0878x; 1.0878x over previous
//
#include <hip/hip_runtime.h>

#define N_NODES 100000
#define N_EDGES 1600000
#define N_GRAPHS 64

typedef __attribute__((ext_vector_type(8))) short bf16x8;
typedef __attribute__((ext_vector_type(4))) float f32x4;

// fp32 -> bf16 with round-to-nearest-even
__device__ __forceinline__ unsigned int f2bf(float f) {
  unsigned int u = __float_as_uint(f);
  return (u + 0x7FFFu + ((u >> 16) & 1u)) >> 16;
}
#define BLO(u) __uint_as_float((u) << 16)
#define BHI(u) __uint_as_float((u) & 0xFFFF0000u)

// pack 8 fp32 into hi bf16x8 (uint4) and lo-residual bf16x8 (uint4).
// Identical decomposition to the old in-register split8: hi=f2bf(v),
// lo=f2bf(v-hi) -> storing it is bit-identical to recomputing it.
__device__ __forceinline__ void pack_hilo8(const float* v, uint4& hi, uint4& lo) {
  unsigned hb_[8], lb_[8];
#pragma unroll
  for (int i = 0; i < 8; ++i) {
    hb_[i] = f2bf(v[i]);
    lb_[i] = f2bf(v[i] - __uint_as_float(hb_[i] << 16));
  }
  hi.x = hb_[0] | (hb_[1] << 16); hi.y = hb_[2] | (hb_[3] << 16);
  hi.z = hb_[4] | (hb_[5] << 16); hi.w = hb_[6] | (hb_[7] << 16);
  lo.x = lb_[0] | (lb_[1] << 16); lo.y = lb_[2] | (lb_[3] << 16);
  lo.z = lb_[4] | (lb_[5] << 16); lo.w = lb_[6] | (lb_[7] << 16);
}

// ---------------- CSR build ----------------

__global__ __launch_bounds__(256) void k_zero_int(int* __restrict__ p, int n) {
  int i = blockIdx.x * 256 + threadIdx.x;
  if (i < n) p[i] = 0;
}

__global__ __launch_bounds__(256) void k_hist(const int* __restrict__ ei, int* __restrict__ deg) {
  int e = blockIdx.x * 256 + threadIdx.x;
  if (e < N_EDGES) atomicAdd(&deg[ei[N_EDGES + e]], 1);
}

__global__ __launch_bounds__(256) void k_scan1(const int* __restrict__ deg, int* __restrict__ part,
                                               int* __restrict__ bsum) {
  __shared__ int tmp[256];
  int i = blockIdx.x * 256 + threadIdx.x;
  int v = (i < N_NODES) ? deg[i] : 0;
  tmp[threadIdx.x] = v;
  __syncthreads();
  for (int o = 1; o < 256; o <<= 1) {
    int t = (threadIdx.x >= o) ? tmp[threadIdx.x - o] : 0;
    __syncthreads();
    tmp[threadIdx.x] += t;
    __syncthreads();
  }
  if (i < N_NODES) part[i] = tmp[threadIdx.x] - v;  // exclusive
  if (threadIdx.x == 255) bsum[blockIdx.x] = tmp[255];
}

__global__ __launch_bounds__(512) void k_scan2(const int* __restrict__ bsum, int* __restrict__ boff, int nb) {
  __shared__ int tmp[512];
  int v = ((int)threadIdx.x < nb) ? bsum[threadIdx.x] : 0;
  tmp[threadIdx.x] = v;
  __syncthreads();
  for (int o = 1; o < 512; o <<= 1) {
    int t = (threadIdx.x >= o) ? tmp[threadIdx.x - o] : 0;
    __syncthreads();
    tmp[threadIdx.x] += t;
    __syncthreads();
  }
  if ((int)threadIdx.x < nb) boff[threadIdx.x] = tmp[threadIdx.x] - v;  // exclusive
}

__global__ __launch_bounds__(256) void k_scan3(const int* __restrict__ part, const int* __restrict__ boff,
                                               int* __restrict__ rowptr, int* __restrict__ cursor) {
  int i = blockIdx.x * 256 + threadIdx.x;
  if (i < N_NODES) {
    int r = part[i] + boff[i >> 8];
    rowptr[i] = r;
    cursor[i] = r;
  } else if (i == N_NODES) {
    rowptr[N_NODES] = N_EDGES;
  }
}

// XCD-partitioned windowed fill (round 6; NT reverted — round 12 showed
// NT loads raise latency on this latency/atomic-bound kernel).
#define FW_NPW 12500
#define FW_EPS 12500
__global__ __launch_bounds__(256) void k_fill_win(const int* __restrict__ ei, int* __restrict__ cursor,
                                                  int* __restrict__ csr) {
  int bid = blockIdx.x;
  int w = bid & 7;
  int s = bid >> 3;
  int lo = w * FW_NPW, hi = lo + FW_NPW;
  int e0 = s * FW_EPS, e1 = e0 + FW_EPS;
  for (int e = e0 + threadIdx.x; e < e1; e += 256) {
    int d = ei[N_EDGES + e];
    if (d >= lo && d < hi) {
      int p = atomicAdd(&cursor[d], 1);
      csr[p] = ei[e];
    }
  }
}

// ---------------- weight prep: transposed hi/lo bf16 split ----------------
__global__ __launch_bounds__(256) void k_prep_w(const float* __restrict__ w, unsigned short* __restrict__ wt) {
  int t = blockIdx.x * 256 + threadIdx.x;  // 16384 threads
  int k = t >> 7, c = t & 127;
  float v = w[k * 128 + c];
  unsigned int hi = f2bf(v);
  float vhi = __uint_as_float(hi << 16);
  unsigned int lo = f2bf(v - vhi);
  wt[c * 256 + k] = (unsigned short)hi;
  wt[c * 256 + k + 128] = (unsigned short)lo;
}

// ---------------- Layer 1 (IN_CH=4) ----------------

__global__ __launch_bounds__(256) void k_l1_agg(const float* __restrict__ x, const int* __restrict__ rowptr,
                                                const int* __restrict__ csr, float* __restrict__ agg4) {
  int t = blockIdx.x * 256 + threadIdx.x;
  if (t >= N_NODES * 4) return;
  int node = t >> 2, c = t & 3;
  int s = rowptr[node], e = rowptr[node + 1];
  float a = 0.f;
  for (int p = s; p < e; ++p) a += x[(size_t)csr[p] * 4 + c];
  agg4[t] = a;
}

// emits hi/lo bf16 state pair (hi feeds gather; hi+lo is the root operand)
__global__ __launch_bounds__(256) void k_l1_comb(const float* __restrict__ x, const float* __restrict__ agg4,
                                                 const float* __restrict__ w_rel, const float* __restrict__ b_rel,
                                                 const float* __restrict__ w_root,
                                                 unsigned short* __restrict__ hh, unsigned short* __restrict__ hl) {
  int t = blockIdx.x * 256 + threadIdx.x;
  int node = t >> 7, c = t & 127;
  if (node >= N_NODES) return;
  float acc = b_rel[c];
#pragma unroll
  for (int k = 0; k < 4; ++k) acc += agg4[node * 4 + k] * w_rel[k * 128 + c];
#pragma unroll
  for (int k = 0; k < 4; ++k) acc += x[node * 4 + k] * w_root[k * 128 + c];
  float r = fmaxf(acc, 0.f);
  unsigned int hb_ = f2bf(r);
  hh[(size_t)node * 128 + c] = (unsigned short)hb_;
  hl[(size_t)node * 128 + c] = (unsigned short)f2bf(r - __uint_as_float(hb_ << 16));
}

// ---------------- Layers 2-4: bf16 gather-sum -> hi/lo agg pair ------------
// 16 lanes per dst row, uint4/lane (8 bf16 = 16B) => 256B/row coalesced.
// unroll 8: 8 uint4 in flight per lane. fp32 accumulate, hi/lo emit.
#define AGG_ACC(U)                                                    \
  a0.x += BLO((U).x); a0.y += BHI((U).x);                             \
  a0.z += BLO((U).y); a0.w += BHI((U).y);                             \
  a1.x += BLO((U).z); a1.y += BHI((U).z);                             \
  a1.z += BLO((U).w); a1.w += BHI((U).w);

__global__ __launch_bounds__(256) void k_agg_bf(const unsigned short* __restrict__ hh,
                                                const int* __restrict__ rowptr, const int* __restrict__ csr,
                                                unsigned short* __restrict__ aggh,
                                                unsigned short* __restrict__ aggl) {
  int node = (blockIdx.x * 256 + threadIdx.x) >> 4;
  int l = threadIdx.x & 15;
  if (node >= N_NODES) return;
  int s = rowptr[node], e = rowptr[node + 1];
  float4 a0 = make_float4(0.f, 0.f, 0.f, 0.f);
  float4 a1 = make_float4(0.f, 0.f, 0.f, 0.f);
  int p = s;
  for (; p + 8 <= e; p += 8) {
    int s0 = csr[p], s1 = csr[p + 1], s2 = csr[p + 2], s3 = csr[p + 3];
    int s4 = csr[p + 4], s5 = csr[p + 5], s6 = csr[p + 6], s7 = csr[p + 7];
    uint4 u0 = *(const uint4*)&hh[(size_t)s0 * 128 + l * 8];
    uint4 u1 = *(const uint4*)&hh[(size_t)s1 * 128 + l * 8];
    uint4 u2 = *(const uint4*)&hh[(size_t)s2 * 128 + l * 8];
    uint4 u3 = *(const uint4*)&hh[(size_t)s3 * 128 + l * 8];
    uint4 u4 = *(const uint4*)&hh[(size_t)s4 * 128 + l * 8];
    uint4 u5 = *(const uint4*)&hh[(size_t)s5 * 128 + l * 8];
    uint4 u6 = *(const uint4*)&hh[(size_t)s6 * 128 + l * 8];
    uint4 u7 = *(const uint4*)&hh[(size_t)s7 * 128 + l * 8];
    AGG_ACC(u0) AGG_ACC(u1) AGG_ACC(u2) AGG_ACC(u3)
    AGG_ACC(u4) AGG_ACC(u5) AGG_ACC(u6) AGG_ACC(u7)
  }
  for (; p + 4 <= e; p += 4) {
    int s0 = csr[p], s1 = csr[p + 1], s2 = csr[p + 2], s3 = csr[p + 3];
    uint4 u0 = *(const uint4*)&hh[(size_t)s0 * 128 + l * 8];
    uint4 u1 = *(const uint4*)&hh[(size_t)s1 * 128 + l * 8];
    uint4 u2 = *(const uint4*)&hh[(size_t)s2 * 128 + l * 8];
    uint4 u3 = *(const uint4*)&hh[(size_t)s3 * 128 + l * 8];
    AGG_ACC(u0) AGG_ACC(u1) AGG_ACC(u2) AGG_ACC(u3)
  }
  for (; p < e; ++p) {
    int s0 = csr[p];
    uint4 u = *(const uint4*)&hh[(size_t)s0 * 128 + l * 8];
    AGG_ACC(u)
  }
  float v[8] = {a0.x, a0.y, a0.z, a0.w, a1.x, a1.y, a1.z, a1.w};
  uint4 hi, lo;
  pack_hilo8(v, hi, lo);
  *(uint4*)&aggh[(size_t)node * 128 + l * 8] = hi;
  *(uint4*)&aggl[(size_t)node * 128 + l * 8] = lo;
}

// ---------------- Layers 2-4: MFMA dual GEMM, pre-split A, staged B --------
// out = relu(agg @ w_rel + h @ w_root + bias). A operands arrive as hi/lo
// bf16 pairs (bit-identical to the old in-register split8 of fp32).
// Per K-frag: A_hi@W_hi + A_hi@W_lo + A_lo@W_hi. B staged/swizzled in LDS
// (round 10). Intermediate layers write the hi/lo pair (in-place safe:
// block reads only its own 64 rows first); last layer writes fp32 for pool.
__global__ __launch_bounds__(256) void k_gemm_mfma4(
    const unsigned short* __restrict__ aggh, const unsigned short* __restrict__ aggl,
    const unsigned short* __restrict__ hh, const unsigned short* __restrict__ hl,
    const unsigned short* __restrict__ wrelT, const unsigned short* __restrict__ wrootT,
    const float* __restrict__ bias, const int last,
    float* __restrict__ fout,
    unsigned short* __restrict__ hho, unsigned short* __restrict__ hlo) {
  __shared__ char lds[32768];
  const int tid = threadIdx.x;
  const int wave = tid >> 6;
  const int lane = tid & 63;
  const int l15 = lane & 15;
  const int lg = lane >> 4;
  const int rb = blockIdx.x * 64 + wave * 16;
  int ar = rb + l15;
  if (ar >= N_NODES) ar = N_NODES - 1;

  f32x4 acc[8];
#pragma unroll
  for (int i = 0; i < 8; ++i) acc[i] = (f32x4){0.f, 0.f, 0.f, 0.f};

#pragma unroll
  for (int src = 0; src < 2; ++src) {
    const unsigned short* Ah = src ? hh : aggh;
    const unsigned short* Al = src ? hl : aggl;
    const unsigned short* W = src ? wrootT : wrelT;
    const size_t abase = (size_t)ar * 128 + lg * 8;
    bf16x8 ah0 = *(const bf16x8*)&Ah[abase];
    bf16x8 ah1 = *(const bf16x8*)&Ah[abase + 32];
    bf16x8 ah2 = *(const bf16x8*)&Ah[abase + 64];
    bf16x8 ah3 = *(const bf16x8*)&Ah[abase + 96];
    bf16x8 al0 = *(const bf16x8*)&Al[abase];
    bf16x8 al1 = *(const bf16x8*)&Al[abase + 32];
    bf16x8 al2 = *(const bf16x8*)&Al[abase + 64];
    bf16x8 al3 = *(const bf16x8*)&Al[abase + 96];
#pragma unroll
    for (int half = 0; half < 2; ++half) {
      __syncthreads();  // previous chunk's readers done
      const unsigned short* wsrc = W + half * 16384;
#pragma unroll
      for (int i = 0; i < 8; ++i) {
        int f = i * 2048 + tid * 8;
        int col = f >> 8;
        int kb2 = (f & 255) * 2;
        uint4 v = *(const uint4*)(wsrc + f);
        *(uint4*)&lds[col * 512 + (kb2 ^ ((col & 7) << 4))] = v;
      }
      __syncthreads();
#pragma unroll
      for (int c0l = 0; c0l < 4; ++c0l) {
        const int c0 = half * 4 + c0l;
        const int cl = c0l * 16 + l15;
        const char* bp = lds + cl * 512;
        const int sw = (cl & 7) << 4;
        const int o = lg * 16;
        bf16x8 bh0 = *(const bf16x8*)(bp + ((o) ^ sw));
        bf16x8 bh1 = *(const bf16x8*)(bp + ((64 + o) ^ sw));
        bf16x8 bh2 = *(const bf16x8*)(bp + ((128 + o) ^ sw));
        bf16x8 bh3 = *(const bf16x8*)(bp + ((192 + o) ^ sw));
        bf16x8 bl0 = *(const bf16x8*)(bp + ((256 + o) ^ sw));
        bf16x8 bl1 = *(const bf16x8*)(bp + ((320 + o) ^ sw));
        bf16x8 bl2 = *(const bf16x8*)(bp + ((384 + o) ^ sw));
        bf16x8 bl3 = *(const bf16x8*)(bp + ((448 + o) ^ sw));
        acc[c0] = __builtin_amdgcn_mfma_f32_16x16x32_bf16(ah0, bh0, acc[c0], 0, 0, 0);
        acc[c0] = __builtin_amdgcn_mfma_f32_16x16x32_bf16(ah1, bh1, acc[c0], 0, 0, 0);
        acc[c0] = __builtin_amdgcn_mfma_f32_16x16x32_bf16(ah2, bh2, acc[c0], 0, 0, 0);
        acc[c0] = __builtin_amdgcn_mfma_f32_16x16x32_bf16(ah3, bh3, acc[c0], 0, 0, 0);
        acc[c0] = __builtin_amdgcn_mfma_f32_16x16x32_bf16(ah0, bl0, acc[c0], 0, 0, 0);
        acc[c0] = __builtin_amdgcn_mfma_f32_16x16x32_bf16(ah1, bl1, acc[c0], 0, 0, 0);
        acc[c0] = __builtin_amdgcn_mfma_f32_16x16x32_bf16(ah2, bl2, acc[c0], 0, 0, 0);
        acc[c0] = __builtin_amdgcn_mfma_f32_16x16x32_bf16(ah3, bl3, acc[c0], 0, 0, 0);
        acc[c0] = __builtin_amdgcn_mfma_f32_16x16x32_bf16(al0, bh0, acc[c0], 0, 0, 0);
        acc[c0] = __builtin_amdgcn_mfma_f32_16x16x32_bf16(al1, bh1, acc[c0], 0, 0, 0);
        acc[c0] = __builtin_amdgcn_mfma_f32_16x16x32_bf16(al2, bh2, acc[c0], 0, 0, 0);
        acc[c0] = __builtin_amdgcn_mfma_f32_16x16x32_bf16(al3, bh3, acc[c0], 0, 0, 0);
      }
    }
  }

#pragma unroll
  for (int c0 = 0; c0 < 8; ++c0) {
    const int c = c0 * 16 + l15;
    const float bi = bias[c];
#pragma unroll
    for (int j = 0; j < 4; ++j) {
      const int row = rb + lg * 4 + j;
      if (row < N_NODES) {
        float v = fmaxf(acc[c0][j] + bi, 0.f);
        if (last) {
          fout[(size_t)row * 128 + c] = v;
        } else {
          unsigned int hb_ = f2bf(v);
          hho[(size_t)row * 128 + c] = (unsigned short)hb_;
          hlo[(size_t)row * 128 + c] = (unsigned short)f2bf(v - __uint_as_float(hb_ << 16));
        }
      }
    }
  }
}

// ---------------- Pooling ----------------

__device__ __forceinline__ int lower_bound_batch(const int* __restrict__ batch, int key) {
  int lo = 0, hi = N_NODES;
  while (lo < hi) {
    int mid = (lo + hi) >> 1;
    if (batch[mid] < key) lo = mid + 1;
    else hi = mid;
  }
  return lo;
}

__global__ __launch_bounds__(256) void k_pool1(const float* __restrict__ h, const int* __restrict__ batch,
                                               float* __restrict__ psum, float* __restrict__ pmax) {
  int b = blockIdx.x;
  int g = b >> 2, q = b & 3;
  int start = lower_bound_batch(batch, g);
  int end = lower_bound_batch(batch, g + 1);
  int c = threadIdx.x & 127;
  int half = threadIdx.x >> 7;
  float sum = 0.f, mx = -3.0e38f;
  for (int n = start + q * 2 + half; n < end; n += 8) {
    float v = h[(size_t)n * 128 + c];
    sum += v;
    mx = fmaxf(mx, v);
  }
  __shared__ float ss[128], sm[128];
  if (half == 0) { ss[c] = sum; sm[c] = mx; }
  __syncthreads();
  if (half == 1) { ss[c] += sum; sm[c] = fmaxf(sm[c], mx); }
  __syncthreads();
  if (half == 0) {
    psum[(size_t)b * 128 + c] = ss[c];
    pmax[(size_t)b * 128 + c] = sm[c];
  }
}

__global__ __launch_bounds__(128) void k_pool2(const float* __restrict__ psum, const float* __restrict__ pmax,
                                               const int* __restrict__ batch, float* __restrict__ pooled) {
  int g = blockIdx.x;
  int c = threadIdx.x;
  int start = lower_bound_batch(batch, g), end = lower_bound_batch(batch, g + 1);
  int count = end - start;
  float s = 0.f, m = -3.0e38f;
#pragma unroll
  for (int q = 0; q < 4; ++q) {
    s += psum[(size_t)(g * 4 + q) * 128 + c];
    m = fmaxf(m, pmax[(size_t)(g * 4 + q) * 128 + c]);
  }
  pooled[(size_t)g * 256 + c] = (count > 0) ? m : 0.f;
  pooled[(size_t)g * 256 + 128 + c] = s / fmaxf((float)count, 1.f);
}

// ---------------- Final FC (fused metadata branch) ----------------

__global__ __launch_bounds__(128) void k_fc(const float* __restrict__ pooled, const float* __restrict__ metadata,
                                            const float* __restrict__ convm_w, const float* __restrict__ convm_b,
                                            const float* __restrict__ fc_w, const float* __restrict__ fc_b,
                                            const float* __restrict__ fc2_w, const float* __restrict__ fc2_b,
                                            float* __restrict__ out) {
  int g = blockIdx.x;
  int tid = threadIdx.x;
  __shared__ float xc[260];
  xc[tid] = pooled[(size_t)g * 256 + tid];
  xc[128 + tid] = pooled[(size_t)g * 256 + 128 + tid];
  if (tid < 4) xc[256 + tid] = fmaxf(metadata[g] * convm_w[tid] + convm_b[tid], 0.f);
  __syncthreads();
  float acc = fc_b[tid];
  for (int k = 0; k < 260; ++k) acc += xc[k] * fc_w[(size_t)k * 128 + tid];
  float partial = fmaxf(acc, 0.f) * fc2_w[tid];
#pragma unroll
  for (int off = 32; off > 0; off >>= 1) partial += __shfl_down(partial, off);
  __shared__ float wred[2];
  if ((tid & 63) == 0) wred[tid >> 6] = partial;
  __syncthreads();
  if (tid == 0) out[g] = wred[0] + wred[1] + fc2_b[0];
}

// ---------------- launch ----------------

extern "C" void kernel_launch(void* const* d_in, const int* in_sizes, int n_in,
                              void* d_out, int out_size, void* d_ws, size_t ws_size,
                              hipStream_t stream) {
  const float* x = (const float*)d_in[0];
  const float* metadata = (const float*)d_in[1];
  const int* ei = (const int*)d_in[2];
  const int* batch = (const int*)d_in[3];
  const float* w_rel[4] = {(const float*)d_in[4], (const float*)d_in[7], (const float*)d_in[10], (const float*)d_in[13]};
  const float* b_rel[4] = {(const float*)d_in[5], (const float*)d_in[8], (const float*)d_in[11], (const float*)d_in[14]};
  const float* w_root[4] = {(const float*)d_in[6], (const float*)d_in[9], (const float*)d_in[12], (const float*)d_in[15]};
  const float* convm_w = (const float*)d_in[16];
  const float* convm_b = (const float*)d_in[17];
  const float* fc_w = (const float*)d_in[18];
  const float* fc_b = (const float*)d_in[19];
  const float* fc2_w = (const float*)d_in[20];
  const float* fc2_b = (const float*)d_in[21];
  float* out = (float*)d_out;

  char* ws = (char*)d_ws;
  size_t off = 0;
  auto alloc = [&](size_t bytes) {
    off = (off + 255) & ~(size_t)255;
    void* p = ws + off;
    off += bytes;
    return p;
  };
  int* deg = (int*)alloc((size_t)N_NODES * 4);
  int* rowptr = (int*)alloc((size_t)(N_NODES + 1) * 4);
  int* cursor = (int*)alloc((size_t)N_NODES * 4);
  int* bsum = (int*)alloc(512 * 4);
  int* boff = (int*)alloc(512 * 4);
  int* csr = (int*)alloc((size_t)N_EDGES * 4);
  float* agg4 = (float*)alloc((size_t)N_NODES * 4 * 4);
  float* bufA = (float*)alloc((size_t)N_NODES * 128 * 4);                     // final h fp32 (pooling)
  unsigned short* hh = (unsigned short*)alloc((size_t)N_NODES * 128 * 2);     // h hi bf16 (gather src)
  unsigned short* hl = (unsigned short*)alloc((size_t)N_NODES * 128 * 2);     // h lo residual
  unsigned short* aggh = (unsigned short*)alloc((size_t)N_NODES * 128 * 2);   // agg hi bf16
  unsigned short* aggl = (unsigned short*)alloc((size_t)N_NODES * 128 * 2);   // agg lo residual
  unsigned short* wt = (unsigned short*)alloc((size_t)6 * 128 * 256 * 2);     // transposed hi/lo weights
  float* psum = (float*)alloc((size_t)256 * 128 * 4);
  float* pmax = (float*)alloc((size_t)256 * 128 * 4);
  float* pooled = (float*)alloc((size_t)64 * 256 * 4);

  const int nblk_nodes = (N_NODES + 255) / 256;
  const int nblk_edges = (N_EDGES + 255) / 256;

  // weight prep (independent)
  for (int l = 1; l < 4; ++l) {
    k_prep_w<<<64, 256, 0, stream>>>(w_rel[l], wt + (size_t)(2 * (l - 1)) * 32768);
    k_prep_w<<<64, 256, 0, stream>>>(w_root[l], wt + (size_t)(2 * (l - 1) + 1) * 32768);
  }

  // CSR build
  k_zero_int<<<nblk_nodes, 256, 0, stream>>>(deg, N_NODES);
  k_hist<<<nblk_edges, 256, 0, stream>>>(ei, deg);
  k_scan1<<<nblk_nodes, 256, 0, stream>>>(deg, rowptr, bsum);
  k_scan2<<<1, 512, 0, stream>>>(bsum, boff, nblk_nodes);
  k_scan3<<<(N_NODES + 1 + 255) / 256, 256, 0, stream>>>(rowptr, boff, rowptr, cursor);
  k_fill_win<<<8 * 128, 256, 0, stream>>>(ei, cursor, csr);

  // Layer 1 (fp32 math, hi/lo output)
  k_l1_agg<<<(N_NODES * 4 + 255) / 256, 256, 0, stream>>>(x, rowptr, csr, agg4);
  k_l1_comb<<<(N_NODES * 128 + 255) / 256, 256, 0, stream>>>(x, agg4, w_rel[0], b_rel[0], w_root[0], hh, hl);

  // Layers 2-4: gather (hh -> aggh/aggl), MFMA GEMM (agg,h -> h in-place | bufA)
  for (int l = 1; l < 4; ++l) {
    k_agg_bf<<<(N_NODES * 16 + 255) / 256, 256, 0, stream>>>(hh, rowptr, csr, aggh, aggl);
    k_gemm_mfma4<<<(N_NODES + 63) / 64, 256, 0, stream>>>(
        aggh, aggl, hh, hl,
        wt + (size_t)(2 * (l - 1)) * 32768, wt + (size_t)(2 * (l - 1) + 1) * 32768,
        b_rel[l], (l == 3) ? 1 : 0, bufA, hh, hl);
  }

  // Pool + FC
  k_pool1<<<256, 256, 0, stream>>>(bufA, batch, psum, pmax);
  k_pool2<<<64, 128, 0, stream>>>(psum, pmax, batch, pooled);
  k_fc<<<64, 128, 0, stream>>>(pooled, metadata, convm_w, convm_b, fc_w, fc_b, fc2_w, fc2_b, out);
}